// Round 1
// baseline (516.578 us; speedup 1.0000x reference)
//
#include <hip/hip_runtime.h>

#define Bn 8
#define Cn 256
#define Ln 8192
#define Hn 8
#define Dn 64
#define IN 512
#define M3 1536

typedef __attribute__((ext_vector_type(4))) float f32x4;
typedef __attribute__((ext_vector_type(8))) __bf16 bf16x8;
typedef __attribute__((ext_vector_type(8))) unsigned short us8;

__device__ __forceinline__ float bf2f(unsigned short u) {
  unsigned int i = ((unsigned int)u) << 16;
  return __builtin_bit_cast(float, i);
}
__device__ __forceinline__ unsigned short f2bf(float f) {
  unsigned int i = __builtin_bit_cast(unsigned int, f);
  i += 0x7FFFu + ((i >> 16) & 1u);
  return (unsigned short)(i >> 16);
}
__device__ __forceinline__ bf16x8 asbf(us8 u) { return __builtin_bit_cast(bf16x8, u); }
__device__ __forceinline__ f32x4 mfma16(bf16x8 a, bf16x8 b, f32x4 c) {
  return __builtin_amdgcn_mfma_f32_16x16x32_bf16(a, b, c, 0, 0, 0);
}

// ---------------- K0a: transpose-convert x (B,C,L) f32 -> xT (B,L,C) bf16 --------
__global__ __launch_bounds__(256) void k_xt(const float* __restrict__ x,
                                            unsigned short* __restrict__ xT) {
  __shared__ unsigned short tl[64 * 66];  // [c][l], stride 66 to dodge bank conflicts
  const int t = threadIdx.x;
  const int l0 = blockIdx.x * 64, c0 = blockIdx.y * 64, b = blockIdx.z;
#pragma unroll
  for (int it = 0; it < 4; ++it) {
    int lin = it * 256 + t;
    int c = lin >> 4;
    int l4 = (lin & 15) * 4;
    const float* gp = x + ((size_t)(b * Cn + c0 + c) * Ln + l0 + l4);
    f32x4 v = *(const f32x4*)gp;
    unsigned int p0 = (unsigned int)f2bf(v[0]) | ((unsigned int)f2bf(v[1]) << 16);
    unsigned int p1 = (unsigned int)f2bf(v[2]) | ((unsigned int)f2bf(v[3]) << 16);
    unsigned int* d = (unsigned int*)&tl[c * 66 + l4];
    d[0] = p0;
    d[1] = p1;
  }
  __syncthreads();
#pragma unroll
  for (int it = 0; it < 2; ++it) {
    int lin = it * 256 + t;
    int l = lin >> 3;
    int s = lin & 7;
    unsigned short v[8];
#pragma unroll
    for (int j = 0; j < 8; ++j) v[j] = tl[(s * 8 + j) * 66 + l];
    uint4 pk;
    pk.x = (unsigned)v[0] | ((unsigned)v[1] << 16);
    pk.y = (unsigned)v[2] | ((unsigned)v[3] << 16);
    pk.z = (unsigned)v[4] | ((unsigned)v[5] << 16);
    pk.w = (unsigned)v[6] | ((unsigned)v[7] << 16);
    *(uint4*)&xT[(size_t)(b * Ln + l0 + l) * Cn + c0 + s * 8] = pk;
  }
}

// ---------------- K0b: convert weights to bf16 ----------------------------------
__global__ __launch_bounds__(256) void k_wcv(const float* __restrict__ Wq, const float* __restrict__ Wk,
                                             const float* __restrict__ Wv, const float* __restrict__ Wo,
                                             unsigned short* __restrict__ Wqkv,
                                             unsigned short* __restrict__ Wob) {
  int i = (blockIdx.x * 256 + threadIdx.x) * 4;
  const float* s;
  unsigned short* d;
  if (i < 393216) {
    int p = i >> 17;  // /131072
    int w = i & 131071;
    s = (p == 0 ? Wq : (p == 1 ? Wk : Wv)) + w;
    d = Wqkv + i;
  } else {
    int w = i - 393216;
    s = Wo + w;
    d = Wob + w;
  }
  f32x4 v = *(const f32x4*)s;
  uint2 pk;
  pk.x = (unsigned)f2bf(v[0]) | ((unsigned)f2bf(v[1]) << 16);
  pk.y = (unsigned)f2bf(v[2]) | ((unsigned)f2bf(v[3]) << 16);
  *(uint2*)d = pk;
}

// ---------------- K1: fused QKV projection GEMM ---------------------------------
// S[i][l] = sum_c Wqkv[i][c] * x[b][c][l];  i<512 -> SqT (B,L,512), else Skv (B,1024,L)
__global__ __launch_bounds__(256) void k_proj(const unsigned short* __restrict__ xT,
                                              const unsigned short* __restrict__ Wqkv,
                                              unsigned short* __restrict__ SqT,
                                              unsigned short* __restrict__ Skv) {
  __shared__ unsigned short tl[4][64 * 72];  // per-wave transpose tile, stride 72 (144B, 16B-mult)
  const int tid = threadIdx.x, lane = tid & 63, wave = tid >> 6;
  const int lr = lane & 15, lg = lane >> 4;
  const int n0 = blockIdx.x * 128, m0 = blockIdx.y * 128, b = blockIdx.z;
  const int wm = (wave >> 1) * 64, wn = (wave & 1) * 64;
  f32x4 zero = {0.f, 0.f, 0.f, 0.f};
  f32x4 acc[4][4];
#pragma unroll
  for (int mt = 0; mt < 4; ++mt)
#pragma unroll
    for (int nt = 0; nt < 4; ++nt) acc[mt][nt] = zero;

  const unsigned short* aB = Wqkv + (size_t)(m0 + wm + lr) * Cn;
  const unsigned short* bB = xT + (size_t)(b * Ln + n0 + wn + lr) * Cn;
#pragma unroll 2
  for (int ks = 0; ks < 8; ++ks) {
    const int kc = ks * 32 + lg * 8;
    bf16x8 af[4], bfv[4];
#pragma unroll
    for (int tt = 0; tt < 4; ++tt) af[tt] = asbf(*(const us8*)(aB + tt * 16 * Cn + kc));
#pragma unroll
    for (int tt = 0; tt < 4; ++tt) bfv[tt] = asbf(*(const us8*)(bB + (size_t)tt * 16 * Cn + kc));
#pragma unroll
    for (int mt = 0; mt < 4; ++mt)
#pragma unroll
      for (int nt = 0; nt < 4; ++nt) acc[mt][nt] = mfma16(af[mt], bfv[nt], acc[mt][nt]);
  }

  unsigned short* T = tl[wave];
  if (m0 < IN) {
    // q: LDS [l][i] -> global SqT (B,L,512)
#pragma unroll
    for (int mt = 0; mt < 4; ++mt)
#pragma unroll
      for (int nt = 0; nt < 4; ++nt) {
        int ll = nt * 16 + lr, ii = mt * 16 + lg * 4;
        uint2 pk;
        pk.x = (unsigned)f2bf(acc[mt][nt][0]) | ((unsigned)f2bf(acc[mt][nt][1]) << 16);
        pk.y = (unsigned)f2bf(acc[mt][nt][2]) | ((unsigned)f2bf(acc[mt][nt][3]) << 16);
        *(uint2*)&T[ll * 72 + ii] = pk;
      }
    __syncthreads();
#pragma unroll
    for (int p = 0; p < 8; ++p) {
      int ll = p * 8 + (lane >> 3), s = lane & 7;
      uint4 v = *(const uint4*)&T[ll * 72 + s * 8];
      *(uint4*)&SqT[(size_t)(b * Ln + n0 + wn + ll) * IN + m0 + wm + s * 8] = v;
    }
  } else {
    // k/v: LDS [i][l] -> global Skv (B,1024,L)
#pragma unroll
    for (int mt = 0; mt < 4; ++mt)
#pragma unroll
      for (int nt = 0; nt < 4; ++nt) {
        int ll = nt * 16 + lr, ii = mt * 16 + lg * 4;
#pragma unroll
        for (int r = 0; r < 4; ++r) T[(ii + r) * 72 + ll] = f2bf(acc[mt][nt][r]);
      }
    __syncthreads();
    int chb = m0 - IN + wm;
#pragma unroll
    for (int p = 0; p < 8; ++p) {
      int ii = p * 8 + (lane >> 3), s = lane & 7;
      uint4 v = *(const uint4*)&T[ii * 72 + s * 8];
      *(uint4*)&Skv[(size_t)(b * 1024 + chb + ii) * Ln + n0 + wn + s * 8] = v;
    }
  }
}

// ---------------- K2: context num^T + denom -------------------------------------
// ctxT[b][h][m][d] = sum_l exp(Sk[d][l]) * Sv[m][l] ; den[b][h][d] = sum_l exp(Sk[d][l])
__global__ __launch_bounds__(256) void k_ctx(const unsigned short* __restrict__ Skv,
                                             float* __restrict__ ctxT, float* __restrict__ den) {
  const int tid = threadIdx.x, lane = tid & 63, wave = tid >> 6;
  const int lr = lane & 15, lg = lane >> 4;
  const int ch = blockIdx.x, h = blockIdx.y, b = blockIdx.z;
  const int dh = (wave >> 1) * 32, mh = (wave & 1) * 32;
  f32x4 zero = {0.f, 0.f, 0.f, 0.f};
  f32x4 acc[2][2];
  acc[0][0] = zero; acc[0][1] = zero; acc[1][0] = zero; acc[1][1] = zero;
  float ds0 = 0.f, ds1 = 0.f;
  const unsigned short* kB = Skv + (size_t)(b * 1024 + h * 64 + dh + lr) * Ln + ch * 512;
  const unsigned short* vB = Skv + (size_t)(b * 1024 + 512 + h * 64 + mh + lr) * Ln + ch * 512;
  for (int ks = 0; ks < 16; ++ks) {
    int kc = ks * 32 + lg * 8;
    us8 k0 = *(const us8*)(kB + kc);
    us8 k1 = *(const us8*)(kB + 16 * Ln + kc);
    us8 e0, e1;
#pragma unroll
    for (int j = 0; j < 8; ++j) {
      float a = __expf(bf2f(k0[j]));
      ds0 += a;
      e0[j] = f2bf(a);
      float c2 = __expf(bf2f(k1[j]));
      ds1 += c2;
      e1[j] = f2bf(c2);
    }
    bf16x8 b0 = asbf(*(const us8*)(vB + kc));
    bf16x8 b1 = asbf(*(const us8*)(vB + 16 * Ln + kc));
    acc[0][0] = mfma16(asbf(e0), b0, acc[0][0]);
    acc[0][1] = mfma16(asbf(e0), b1, acc[0][1]);
    acc[1][0] = mfma16(asbf(e1), b0, acc[1][0]);
    acc[1][1] = mfma16(asbf(e1), b1, acc[1][1]);
  }
  float* cbase = ctxT + (size_t)(b * Hn + h) * 4096;
#pragma unroll
  for (int dt = 0; dt < 2; ++dt)
#pragma unroll
    for (int mtt = 0; mtt < 2; ++mtt)
#pragma unroll
      for (int r = 0; r < 4; ++r)
        atomicAdd(&cbase[(size_t)(mh + mtt * 16 + lr) * 64 + dh + dt * 16 + lg * 4 + r],
                  acc[dt][mtt][r]);
  ds0 += __shfl_xor(ds0, 16);
  ds0 += __shfl_xor(ds0, 32);
  ds1 += __shfl_xor(ds1, 16);
  ds1 += __shfl_xor(ds1, 32);
  if ((wave & 1) == 0 && lane < 16) {
    atomicAdd(&den[(b * Hn + h) * 64 + dh + lane], ds0);
    atomicAdd(&den[(b * Hn + h) * 64 + dh + 16 + lane], ds1);
  }
}

// ---------------- K3: q-softmax + out-GEMM + output projection -------------------
__global__ __launch_bounds__(256) void k_out(const unsigned short* __restrict__ SqT,
                                             const float* __restrict__ ctxT,
                                             const float* __restrict__ den,
                                             const unsigned short* __restrict__ Wob,
                                             const float* __restrict__ bo,
                                             float* __restrict__ out) {
  __shared__ unsigned short ot[64 * IN];  // [l][i] bf16, XOR-swizzled 16B slots
  const int tid = threadIdx.x, lane = tid & 63, w = tid >> 6;
  const int lr = lane & 15, lg = lane >> 4;
  const int l0 = blockIdx.x * 64, b = blockIdx.y;
  f32x4 zero = {0.f, 0.f, 0.f, 0.f};

  for (int h = 0; h < Hn; ++h) {
    const unsigned short* qp = SqT + (size_t)(b * Ln + l0 + w * 16 + lr) * IN + h * 64 + lg * 8;
    us8 r0 = *(const us8*)qp;
    us8 r1 = *(const us8*)(qp + 32);
    float qv[16];
#pragma unroll
    for (int j = 0; j < 8; ++j) {
      qv[j] = bf2f(r0[j]);
      qv[8 + j] = bf2f(r1[j]);
    }
    float mx = qv[0];
#pragma unroll
    for (int j = 1; j < 16; ++j) mx = fmaxf(mx, qv[j]);
    mx = fmaxf(mx, __shfl_xor(mx, 16));
    mx = fmaxf(mx, __shfl_xor(mx, 32));
    float sm = 0.f;
#pragma unroll
    for (int j = 0; j < 16; ++j) {
      qv[j] = __expf(qv[j] - mx);
      sm += qv[j];
    }
    sm += __shfl_xor(sm, 16);
    sm += __shfl_xor(sm, 32);
    float rs = 1.0f / sm;
    us8 a0u, a1u;
#pragma unroll
    for (int j = 0; j < 8; ++j) {
      a0u[j] = f2bf(qv[j] * rs);
      a1u[j] = f2bf(qv[8 + j] * rs);
    }
    bf16x8 a0 = asbf(a0u), a1 = asbf(a1u);
    const float* dn = den + (b * Hn + h) * 64;
    float rd0[8], rd1[8];
#pragma unroll
    for (int j = 0; j < 8; ++j) {
      rd0[j] = 1.0f / dn[lg * 8 + j];
      rd1[j] = 1.0f / dn[32 + lg * 8 + j];
    }
    const float* cb = ctxT + (size_t)(b * Hn + h) * 4096;
#pragma unroll
    for (int mt = 0; mt < 4; ++mt) {
      const float* cp = cb + (mt * 16 + lr) * 64 + lg * 8;
      f32x4 c0 = *(const f32x4*)cp;
      f32x4 c1 = *(const f32x4*)(cp + 4);
      f32x4 c2 = *(const f32x4*)(cp + 32);
      f32x4 c3 = *(const f32x4*)(cp + 36);
      us8 bu0, bu1;
#pragma unroll
      for (int j = 0; j < 4; ++j) {
        bu0[j] = f2bf(c0[j] * rd0[j]);
        bu0[4 + j] = f2bf(c1[j] * rd0[4 + j]);
        bu1[j] = f2bf(c2[j] * rd1[j]);
        bu1[4 + j] = f2bf(c3[j] * rd1[4 + j]);
      }
      f32x4 oa = zero;
      oa = mfma16(a0, asbf(bu0), oa);
      oa = mfma16(a1, asbf(bu1), oa);
      int ib = h * 64 + mt * 16 + lr;
#pragma unroll
      for (int r = 0; r < 4; ++r) {
        int ll = w * 16 + lg * 4 + r;
        ot[(ll * IN + ib) ^ ((ll & 7) << 3)] = f2bf(oa[r]);
      }
    }
  }
  __syncthreads();

  f32x4 acc[4][4];
#pragma unroll
  for (int mt = 0; mt < 4; ++mt)
#pragma unroll
    for (int nt = 0; nt < 4; ++nt) acc[mt][nt] = zero;
  const unsigned short* wB = Wob + (size_t)(w * 64 + lr) * IN;
#pragma unroll 2
  for (int ks = 0; ks < 16; ++ks) {
    int kc = ks * 32 + lg * 8;
    bf16x8 af[4], bf4[4];
#pragma unroll
    for (int mt = 0; mt < 4; ++mt) af[mt] = asbf(*(const us8*)(wB + mt * 16 * IN + kc));
#pragma unroll
    for (int nt = 0; nt < 4; ++nt) {
      int ll = nt * 16 + lr;
      bf4[nt] = asbf(*(const us8*)&ot[(ll * IN + kc) ^ ((ll & 7) << 3)]);
    }
#pragma unroll
    for (int mt = 0; mt < 4; ++mt)
#pragma unroll
      for (int nt = 0; nt < 4; ++nt) acc[mt][nt] = mfma16(af[mt], bf4[nt], acc[mt][nt]);
  }
#pragma unroll
  for (int mt = 0; mt < 4; ++mt) {
    int c = w * 64 + mt * 16 + lg * 4;
#pragma unroll
    for (int r = 0; r < 4; ++r) {
      float bb = bo[c + r];
      float* op = out + (size_t)(b * Cn + c + r) * Ln + l0;
#pragma unroll
      for (int nt = 0; nt < 4; ++nt) op[nt * 16 + lr] = acc[mt][nt][r] + bb;
    }
  }
}

extern "C" void kernel_launch(void* const* d_in, const int* in_sizes, int n_in,
                              void* d_out, int out_size, void* d_ws, size_t ws_size,
                              hipStream_t stream) {
  const float* x = (const float*)d_in[0];
  const float* Wq = (const float*)d_in[1];
  const float* Wk = (const float*)d_in[2];
  const float* Wv = (const float*)d_in[3];
  const float* Wo = (const float*)d_in[4];
  const float* bo = (const float*)d_in[5];
  float* out = (float*)d_out;

  char* ws = (char*)d_ws;
  size_t o = 0;
  unsigned short* xT = (unsigned short*)(ws + o);   o += (size_t)Bn * Ln * Cn * 2;    // 33.5 MB
  unsigned short* Wqkv = (unsigned short*)(ws + o); o += (size_t)M3 * Cn * 2;         // 768 KB
  unsigned short* Wob = (unsigned short*)(ws + o);  o += (size_t)Cn * IN * 2;         // 256 KB
  unsigned short* SqT = (unsigned short*)(ws + o);  o += (size_t)Bn * Ln * IN * 2;    // 67 MB
  unsigned short* Skv = (unsigned short*)(ws + o);  o += (size_t)Bn * 1024 * Ln * 2;  // 134 MB
  float* ctxT = (float*)(ws + o);                   o += (size_t)Bn * Hn * 64 * 64 * 4;
  float* den = (float*)(ws + o);                    o += (size_t)Bn * Hn * 64 * 4;
  // total ~226 MB

  hipMemsetAsync(ctxT, 0, (size_t)Bn * Hn * 64 * 64 * 4 + (size_t)Bn * Hn * 64 * 4, stream);
  k_xt<<<dim3(Ln / 64, Cn / 64, Bn), 256, 0, stream>>>(x, xT);
  k_wcv<<<512, 256, 0, stream>>>(Wq, Wk, Wv, Wo, Wqkv, Wob);
  k_proj<<<dim3(Ln / 128, M3 / 128, Bn), 256, 0, stream>>>(xT, Wqkv, SqT, Skv);
  k_ctx<<<dim3(16, Hn, Bn), 256, 0, stream>>>(Skv, ctxT, den);
  k_out<<<dim3(Ln / 64, Bn), 256, 0, stream>>>(SqT, ctxT, den, Wob, bo, out);
}

// Round 2
// 402.316 us; speedup vs baseline: 1.2840x; 1.2840x over previous
//
#include <hip/hip_runtime.h>

#define Bn 8
#define Cn 256
#define Ln 8192
#define Hn 8
#define Dn 64
#define IN 512
#define M3 1536

typedef __attribute__((ext_vector_type(4))) float f32x4;
typedef __attribute__((ext_vector_type(8))) __bf16 bf16x8;
typedef __attribute__((ext_vector_type(8))) unsigned short us8;

__device__ __forceinline__ float bf2f(unsigned short u) {
  unsigned int i = ((unsigned int)u) << 16;
  return __builtin_bit_cast(float, i);
}
__device__ __forceinline__ unsigned short f2bf(float f) {
  unsigned int i = __builtin_bit_cast(unsigned int, f);
  i += 0x7FFFu + ((i >> 16) & 1u);
  return (unsigned short)(i >> 16);
}
__device__ __forceinline__ bf16x8 asbf(us8 u) { return __builtin_bit_cast(bf16x8, u); }
__device__ __forceinline__ f32x4 mfma16(bf16x8 a, bf16x8 b, f32x4 c) {
  return __builtin_amdgcn_mfma_f32_16x16x32_bf16(a, b, c, 0, 0, 0);
}
__device__ __forceinline__ void gll16(const void* g, void* l) {
  __builtin_amdgcn_global_load_lds((const __attribute__((address_space(1))) void*)g,
                                   (__attribute__((address_space(3))) void*)l, 16, 0, 0);
}

// ---------------- K0a: transpose-convert x (B,C,L) f32 -> xT (B,L,C) bf16 --------
__global__ __launch_bounds__(256) void k_xt(const float* __restrict__ x,
                                            unsigned short* __restrict__ xT) {
  __shared__ unsigned short tl[64 * 66];  // [c][l], stride 66 to dodge bank conflicts
  const int t = threadIdx.x;
  const int l0 = blockIdx.x * 64, c0 = blockIdx.y * 64, b = blockIdx.z;
#pragma unroll
  for (int it = 0; it < 4; ++it) {
    int lin = it * 256 + t;
    int c = lin >> 4;
    int l4 = (lin & 15) * 4;
    const float* gp = x + ((size_t)(b * Cn + c0 + c) * Ln + l0 + l4);
    f32x4 v = *(const f32x4*)gp;
    unsigned int p0 = (unsigned int)f2bf(v[0]) | ((unsigned int)f2bf(v[1]) << 16);
    unsigned int p1 = (unsigned int)f2bf(v[2]) | ((unsigned int)f2bf(v[3]) << 16);
    unsigned int* d = (unsigned int*)&tl[c * 66 + l4];
    d[0] = p0;
    d[1] = p1;
  }
  __syncthreads();
#pragma unroll
  for (int it = 0; it < 2; ++it) {
    int lin = it * 256 + t;
    int l = lin >> 3;
    int s = lin & 7;
    unsigned short v[8];
#pragma unroll
    for (int j = 0; j < 8; ++j) v[j] = tl[(s * 8 + j) * 66 + l];
    uint4 pk;
    pk.x = (unsigned)v[0] | ((unsigned)v[1] << 16);
    pk.y = (unsigned)v[2] | ((unsigned)v[3] << 16);
    pk.z = (unsigned)v[4] | ((unsigned)v[5] << 16);
    pk.w = (unsigned)v[6] | ((unsigned)v[7] << 16);
    *(uint4*)&xT[(size_t)(b * Ln + l0 + l) * Cn + c0 + s * 8] = pk;
  }
}

// ---------------- K0b: convert weights to bf16 ----------------------------------
__global__ __launch_bounds__(256) void k_wcv(const float* __restrict__ Wq, const float* __restrict__ Wk,
                                             const float* __restrict__ Wv, const float* __restrict__ Wo,
                                             unsigned short* __restrict__ Wqkv,
                                             unsigned short* __restrict__ Wob) {
  int i = (blockIdx.x * 256 + threadIdx.x) * 4;
  const float* s;
  unsigned short* d;
  if (i < 393216) {
    int p = i >> 17;  // /131072
    int w = i & 131071;
    s = (p == 0 ? Wq : (p == 1 ? Wk : Wv)) + w;
    d = Wqkv + i;
  } else {
    int w = i - 393216;
    s = Wo + w;
    d = Wob + w;
  }
  f32x4 v = *(const f32x4*)s;
  uint2 pk;
  pk.x = (unsigned)f2bf(v[0]) | ((unsigned)f2bf(v[1]) << 16);
  pk.y = (unsigned)f2bf(v[2]) | ((unsigned)f2bf(v[3]) << 16);
  *(uint2*)d = pk;
}

// ---------------- K1: fused QKV projection GEMM (m97-style LDS staging) ----------
// S[i][l] = sum_c Wqkv[i][c] * x[b][c][l];  i<512 -> SqT (B,L,512), else Skv (B,1024,L)
__global__ __launch_bounds__(256) void k_proj(const unsigned short* __restrict__ xT,
                                              const unsigned short* __restrict__ Wqkv,
                                              unsigned short* __restrict__ SqT,
                                              unsigned short* __restrict__ Skv) {
  // staging: Wt[128][64] at lds+0, Xt[128][64] at lds+8192 (shorts). Epilogue
  // reuses the same region as 4 per-wave 64x72 transpose tiles (18432 shorts).
  __shared__ unsigned short lds[18432];
  const int tid = threadIdx.x, lane = tid & 63, wave = tid >> 6;
  const int lr = lane & 15, lg = lane >> 4;
  const int n0 = blockIdx.x * 128, m0 = blockIdx.y * 128, b = blockIdx.z;
  const int wm = (wave >> 1) * 64, wn = (wave & 1) * 64;
  unsigned short* Wt = lds;
  unsigned short* Xt = lds + 8192;

  f32x4 zero = {0.f, 0.f, 0.f, 0.f};
  f32x4 acc[4][4];
#pragma unroll
  for (int mt = 0; mt < 4; ++mt)
#pragma unroll
    for (int nt = 0; nt < 4; ++nt) acc[mt][nt] = zero;

  const int sr = tid >> 3, sc = (tid & 7) * 8;  // stage row 0..31, col-elem 0..56
  const unsigned short* wsrc = Wqkv + (size_t)(m0 + sr) * Cn + sc;
  const unsigned short* xsrc = xT + (size_t)(b * Ln + n0 + sr) * Cn + sc;

  for (int kt = 0; kt < 4; ++kt) {
    const int k0 = kt * 64;
#pragma unroll
    for (int it = 0; it < 4; ++it) {
      gll16(wsrc + (size_t)(it * 32) * Cn + k0, Wt + it * 2048 + tid * 8);
      gll16(xsrc + (size_t)(it * 32) * Cn + k0, Xt + it * 2048 + tid * 8);
    }
    __syncthreads();
#pragma unroll
    for (int ks = 0; ks < 2; ++ks) {
      const int kc = ks * 32 + lg * 8;
      bf16x8 af[4], bfv[4];
#pragma unroll
      for (int mt = 0; mt < 4; ++mt)
        af[mt] = asbf(*(const us8*)(Wt + (wm + mt * 16 + lr) * 64 + kc));
#pragma unroll
      for (int nt = 0; nt < 4; ++nt)
        bfv[nt] = asbf(*(const us8*)(Xt + (wn + nt * 16 + lr) * 64 + kc));
#pragma unroll
      for (int mt = 0; mt < 4; ++mt)
#pragma unroll
        for (int nt = 0; nt < 4; ++nt) acc[mt][nt] = mfma16(af[mt], bfv[nt], acc[mt][nt]);
    }
    __syncthreads();
  }

  unsigned short* T = lds + wave * 4608;  // 64x72 per-wave transpose tile
  if (m0 < IN) {
    // q: LDS [l][i] -> global SqT (B,L,512)
#pragma unroll
    for (int mt = 0; mt < 4; ++mt)
#pragma unroll
      for (int nt = 0; nt < 4; ++nt) {
        int ll = nt * 16 + lr, ii = mt * 16 + lg * 4;
        uint2 pk;
        pk.x = (unsigned)f2bf(acc[mt][nt][0]) | ((unsigned)f2bf(acc[mt][nt][1]) << 16);
        pk.y = (unsigned)f2bf(acc[mt][nt][2]) | ((unsigned)f2bf(acc[mt][nt][3]) << 16);
        *(uint2*)&T[ll * 72 + ii] = pk;
      }
    __syncthreads();
#pragma unroll
    for (int p = 0; p < 8; ++p) {
      int ll = p * 8 + (lane >> 3), s = lane & 7;
      uint4 v = *(const uint4*)&T[ll * 72 + s * 8];
      *(uint4*)&SqT[(size_t)(b * Ln + n0 + wn + ll) * IN + m0 + wm + s * 8] = v;
    }
  } else {
    // k/v: LDS [i][l] -> global Skv (B,1024,L)
#pragma unroll
    for (int mt = 0; mt < 4; ++mt)
#pragma unroll
      for (int nt = 0; nt < 4; ++nt) {
        int ll = nt * 16 + lr, ii = mt * 16 + lg * 4;
#pragma unroll
        for (int r = 0; r < 4; ++r) T[(ii + r) * 72 + ll] = f2bf(acc[mt][nt][r]);
      }
    __syncthreads();
    int chb = m0 - IN + wm;
#pragma unroll
    for (int p = 0; p < 8; ++p) {
      int ii = p * 8 + (lane >> 3), s = lane & 7;
      uint4 v = *(const uint4*)&T[ii * 72 + s * 8];
      *(uint4*)&Skv[(size_t)(b * 1024 + chb + ii) * Ln + n0 + wn + s * 8] = v;
    }
  }
}

// ---------------- K2: context num^T + denom -------------------------------------
// ctxT[b][h][m][d] = sum_l exp(Sk[d][l]) * Sv[m][l] ; den[b][h][d] = sum_l exp(Sk[d][l])
__global__ __launch_bounds__(256) void k_ctx(const unsigned short* __restrict__ Skv,
                                             float* __restrict__ ctxT, float* __restrict__ den) {
  const int tid = threadIdx.x, lane = tid & 63, wave = tid >> 6;
  const int lr = lane & 15, lg = lane >> 4;
  const int ch = blockIdx.x, h = blockIdx.y, b = blockIdx.z;
  const int dh = (wave >> 1) * 32, mh = (wave & 1) * 32;
  f32x4 zero = {0.f, 0.f, 0.f, 0.f};
  f32x4 acc[2][2];
  acc[0][0] = zero; acc[0][1] = zero; acc[1][0] = zero; acc[1][1] = zero;
  float ds0 = 0.f, ds1 = 0.f;
  const unsigned short* kB = Skv + (size_t)(b * 1024 + h * 64 + dh + lr) * Ln + ch * 512;
  const unsigned short* vB = Skv + (size_t)(b * 1024 + 512 + h * 64 + mh + lr) * Ln + ch * 512;
  for (int ks = 0; ks < 16; ++ks) {
    int kc = ks * 32 + lg * 8;
    us8 k0 = *(const us8*)(kB + kc);
    us8 k1 = *(const us8*)(kB + 16 * Ln + kc);
    us8 e0, e1;
#pragma unroll
    for (int j = 0; j < 8; ++j) {
      float a = __expf(bf2f(k0[j]));
      ds0 += a;
      e0[j] = f2bf(a);
      float c2 = __expf(bf2f(k1[j]));
      ds1 += c2;
      e1[j] = f2bf(c2);
    }
    bf16x8 b0 = asbf(*(const us8*)(vB + kc));
    bf16x8 b1 = asbf(*(const us8*)(vB + 16 * Ln + kc));
    acc[0][0] = mfma16(asbf(e0), b0, acc[0][0]);
    acc[0][1] = mfma16(asbf(e0), b1, acc[0][1]);
    acc[1][0] = mfma16(asbf(e1), b0, acc[1][0]);
    acc[1][1] = mfma16(asbf(e1), b1, acc[1][1]);
  }
  float* cbase = ctxT + (size_t)(b * Hn + h) * 4096;
#pragma unroll
  for (int dt = 0; dt < 2; ++dt)
#pragma unroll
    for (int mtt = 0; mtt < 2; ++mtt)
#pragma unroll
      for (int r = 0; r < 4; ++r)
        atomicAdd(&cbase[(size_t)(mh + mtt * 16 + lr) * 64 + dh + dt * 16 + lg * 4 + r],
                  acc[dt][mtt][r]);
  ds0 += __shfl_xor(ds0, 16);
  ds0 += __shfl_xor(ds0, 32);
  ds1 += __shfl_xor(ds1, 16);
  ds1 += __shfl_xor(ds1, 32);
  if ((wave & 1) == 0 && lane < 16) {
    atomicAdd(&den[(b * Hn + h) * 64 + dh + lane], ds0);
    atomicAdd(&den[(b * Hn + h) * 64 + dh + 16 + lane], ds1);
  }
}

// ---------------- K3: q-softmax + out-GEMM + output projection -------------------
__global__ __launch_bounds__(256) void k_out(const unsigned short* __restrict__ SqT,
                                             const float* __restrict__ ctxT,
                                             const float* __restrict__ den,
                                             const unsigned short* __restrict__ Wob,
                                             const float* __restrict__ bo,
                                             float* __restrict__ out) {
  __shared__ unsigned short ot[64 * IN];  // [l][i] bf16, XOR-swizzled 16B slots
  const int tid = threadIdx.x, lane = tid & 63, w = tid >> 6;
  const int lr = lane & 15, lg = lane >> 4;
  const int l0 = blockIdx.x * 64, b = blockIdx.y;
  f32x4 zero = {0.f, 0.f, 0.f, 0.f};

  for (int h = 0; h < Hn; ++h) {
    const unsigned short* qp = SqT + (size_t)(b * Ln + l0 + w * 16 + lr) * IN + h * 64 + lg * 8;
    us8 r0 = *(const us8*)qp;
    us8 r1 = *(const us8*)(qp + 32);
    float qv[16];
#pragma unroll
    for (int j = 0; j < 8; ++j) {
      qv[j] = bf2f(r0[j]);
      qv[8 + j] = bf2f(r1[j]);
    }
    float mx = qv[0];
#pragma unroll
    for (int j = 1; j < 16; ++j) mx = fmaxf(mx, qv[j]);
    mx = fmaxf(mx, __shfl_xor(mx, 16));
    mx = fmaxf(mx, __shfl_xor(mx, 32));
    float sm = 0.f;
#pragma unroll
    for (int j = 0; j < 16; ++j) {
      qv[j] = __expf(qv[j] - mx);
      sm += qv[j];
    }
    sm += __shfl_xor(sm, 16);
    sm += __shfl_xor(sm, 32);
    float rs = 1.0f / sm;
    us8 a0u, a1u;
#pragma unroll
    for (int j = 0; j < 8; ++j) {
      a0u[j] = f2bf(qv[j] * rs);
      a1u[j] = f2bf(qv[8 + j] * rs);
    }
    bf16x8 a0 = asbf(a0u), a1 = asbf(a1u);
    const float* dn = den + (b * Hn + h) * 64;
    float rd0[8], rd1[8];
#pragma unroll
    for (int j = 0; j < 8; ++j) {
      rd0[j] = 1.0f / dn[lg * 8 + j];
      rd1[j] = 1.0f / dn[32 + lg * 8 + j];
    }
    const float* cb = ctxT + (size_t)(b * Hn + h) * 4096;
#pragma unroll
    for (int mt = 0; mt < 4; ++mt) {
      const float* cp = cb + (mt * 16 + lr) * 64 + lg * 8;
      f32x4 c0 = *(const f32x4*)cp;
      f32x4 c1 = *(const f32x4*)(cp + 4);
      f32x4 c2 = *(const f32x4*)(cp + 32);
      f32x4 c3 = *(const f32x4*)(cp + 36);
      us8 bu0, bu1;
#pragma unroll
      for (int j = 0; j < 4; ++j) {
        bu0[j] = f2bf(c0[j] * rd0[j]);
        bu0[4 + j] = f2bf(c1[j] * rd0[4 + j]);
        bu1[j] = f2bf(c2[j] * rd1[j]);
        bu1[4 + j] = f2bf(c3[j] * rd1[4 + j]);
      }
      f32x4 oa = zero;
      oa = mfma16(a0, asbf(bu0), oa);
      oa = mfma16(a1, asbf(bu1), oa);
      int ib = h * 64 + mt * 16 + lr;
#pragma unroll
      for (int r = 0; r < 4; ++r) {
        int ll = w * 16 + lg * 4 + r;
        ot[(ll * IN + ib) ^ ((ll & 7) << 3)] = f2bf(oa[r]);
      }
    }
  }
  __syncthreads();

  f32x4 acc[4][4];
#pragma unroll
  for (int mt = 0; mt < 4; ++mt)
#pragma unroll
    for (int nt = 0; nt < 4; ++nt) acc[mt][nt] = zero;
  const unsigned short* wB = Wob + (size_t)(w * 64 + lr) * IN;
#pragma unroll 2
  for (int ks = 0; ks < 16; ++ks) {
    int kc = ks * 32 + lg * 8;
    bf16x8 af[4], bf4[4];
#pragma unroll
    for (int mt = 0; mt < 4; ++mt) af[mt] = asbf(*(const us8*)(wB + mt * 16 * IN + kc));
#pragma unroll
    for (int nt = 0; nt < 4; ++nt) {
      int ll = nt * 16 + lr;
      bf4[nt] = asbf(*(const us8*)&ot[(ll * IN + kc) ^ ((ll & 7) << 3)]);
    }
#pragma unroll
    for (int mt = 0; mt < 4; ++mt)
#pragma unroll
      for (int nt = 0; nt < 4; ++nt) acc[mt][nt] = mfma16(af[mt], bf4[nt], acc[mt][nt]);
  }
#pragma unroll
  for (int mt = 0; mt < 4; ++mt) {
    int c = w * 64 + mt * 16 + lg * 4;
#pragma unroll
    for (int r = 0; r < 4; ++r) {
      float bb = bo[c + r];
      float* op = out + (size_t)(b * Cn + c + r) * Ln + l0;
#pragma unroll
      for (int nt = 0; nt < 4; ++nt) op[nt * 16 + lr] = acc[mt][nt][r] + bb;
    }
  }
}

extern "C" void kernel_launch(void* const* d_in, const int* in_sizes, int n_in,
                              void* d_out, int out_size, void* d_ws, size_t ws_size,
                              hipStream_t stream) {
  const float* x = (const float*)d_in[0];
  const float* Wq = (const float*)d_in[1];
  const float* Wk = (const float*)d_in[2];
  const float* Wv = (const float*)d_in[3];
  const float* Wo = (const float*)d_in[4];
  const float* bo = (const float*)d_in[5];
  float* out = (float*)d_out;

  char* ws = (char*)d_ws;
  size_t o = 0;
  unsigned short* xT = (unsigned short*)(ws + o);   o += (size_t)Bn * Ln * Cn * 2;    // 33.5 MB
  unsigned short* Wqkv = (unsigned short*)(ws + o); o += (size_t)M3 * Cn * 2;         // 768 KB
  unsigned short* Wob = (unsigned short*)(ws + o);  o += (size_t)Cn * IN * 2;         // 256 KB
  unsigned short* SqT = (unsigned short*)(ws + o);  o += (size_t)Bn * Ln * IN * 2;    // 67 MB
  unsigned short* Skv = (unsigned short*)(ws + o);  o += (size_t)Bn * 1024 * Ln * 2;  // 134 MB
  float* ctxT = (float*)(ws + o);                   o += (size_t)Bn * Hn * 64 * 64 * 4;
  float* den = (float*)(ws + o);                    o += (size_t)Bn * Hn * 64 * 4;
  // total ~226 MB

  hipMemsetAsync(ctxT, 0, (size_t)Bn * Hn * 64 * 64 * 4 + (size_t)Bn * Hn * 64 * 4, stream);
  k_xt<<<dim3(Ln / 64, Cn / 64, Bn), 256, 0, stream>>>(x, xT);
  k_wcv<<<512, 256, 0, stream>>>(Wq, Wk, Wv, Wo, Wqkv, Wob);
  k_proj<<<dim3(Ln / 128, M3 / 128, Bn), 256, 0, stream>>>(xT, Wqkv, SqT, Skv);
  k_ctx<<<dim3(16, Hn, Bn), 256, 0, stream>>>(Skv, ctxT, den);
  k_out<<<dim3(Ln / 64, Bn), 256, 0, stream>>>(SqT, ctxT, den, Wob, bo, out);
}

// Round 3
// 299.922 us; speedup vs baseline: 1.7224x; 1.3414x over previous
//
#include <hip/hip_runtime.h>

#define Bn 8
#define Cn 256
#define Ln 8192
#define Hn 8
#define Dn 64
#define IN 512

typedef __attribute__((ext_vector_type(4))) float f32x4;
typedef __attribute__((ext_vector_type(8))) __bf16 bf16x8;
typedef __attribute__((ext_vector_type(8))) unsigned short us8;

__device__ __forceinline__ float bf2f(unsigned short u) {
  unsigned int i = ((unsigned int)u) << 16;
  return __builtin_bit_cast(float, i);
}
__device__ __forceinline__ unsigned short f2bf(float f) {
  unsigned int i = __builtin_bit_cast(unsigned int, f);
  i += 0x7FFFu + ((i >> 16) & 1u);
  return (unsigned short)(i >> 16);
}
__device__ __forceinline__ bf16x8 asbf(us8 u) { return __builtin_bit_cast(bf16x8, u); }
__device__ __forceinline__ f32x4 mfma16(bf16x8 a, bf16x8 b, f32x4 c) {
  return __builtin_amdgcn_mfma_f32_16x16x32_bf16(a, b, c, 0, 0, 0);
}
__device__ __forceinline__ void gll16(const void* g, void* l) {
  __builtin_amdgcn_global_load_lds((const __attribute__((address_space(1))) void*)g,
                                   (__attribute__((address_space(3))) void*)l, 16, 0, 0);
}

// ---------------- K0a: transpose-convert x (B,C,L) f32 -> xT (B,L,C) bf16 --------
__global__ __launch_bounds__(256) void k_xt(const float* __restrict__ x,
                                            unsigned short* __restrict__ xT) {
  __shared__ unsigned short tl[64 * 66];
  const int t = threadIdx.x;
  const int l0 = blockIdx.x * 64, c0 = blockIdx.y * 64, b = blockIdx.z;
#pragma unroll
  for (int it = 0; it < 4; ++it) {
    int lin = it * 256 + t;
    int c = lin >> 4;
    int l4 = (lin & 15) * 4;
    const float* gp = x + ((size_t)(b * Cn + c0 + c) * Ln + l0 + l4);
    f32x4 v = *(const f32x4*)gp;
    unsigned int p0 = (unsigned int)f2bf(v[0]) | ((unsigned int)f2bf(v[1]) << 16);
    unsigned int p1 = (unsigned int)f2bf(v[2]) | ((unsigned int)f2bf(v[3]) << 16);
    unsigned int* d = (unsigned int*)&tl[c * 66 + l4];
    d[0] = p0;
    d[1] = p1;
  }
  __syncthreads();
#pragma unroll
  for (int it = 0; it < 2; ++it) {
    int lin = it * 256 + t;
    int l = lin >> 3;
    int s = lin & 7;
    unsigned short v[8];
#pragma unroll
    for (int j = 0; j < 8; ++j) v[j] = tl[(s * 8 + j) * 66 + l];
    uint4 pk;
    pk.x = (unsigned)v[0] | ((unsigned)v[1] << 16);
    pk.y = (unsigned)v[2] | ((unsigned)v[3] << 16);
    pk.z = (unsigned)v[4] | ((unsigned)v[5] << 16);
    pk.w = (unsigned)v[6] | ((unsigned)v[7] << 16);
    *(uint4*)&xT[(size_t)(b * Ln + l0 + l) * Cn + c0 + s * 8] = pk;
  }
}

// ---------------- K0b: convert weights to bf16 ----------------------------------
__global__ __launch_bounds__(256) void k_wcv(const float* __restrict__ Wq, const float* __restrict__ Wk,
                                             const float* __restrict__ Wv, const float* __restrict__ Wo,
                                             unsigned short* __restrict__ Wqkv,
                                             unsigned short* __restrict__ Wob) {
  int i = (blockIdx.x * 256 + threadIdx.x) * 4;
  const float* s;
  unsigned short* d;
  if (i < 393216) {
    int p = i >> 17;
    int w = i & 131071;
    s = (p == 0 ? Wq : (p == 1 ? Wk : Wv)) + w;
    d = Wqkv + i;
  } else {
    int w = i - 393216;
    s = Wo + w;
    d = Wob + w;
  }
  f32x4 v = *(const f32x4*)s;
  uint2 pk;
  pk.x = (unsigned)f2bf(v[0]) | ((unsigned)f2bf(v[1]) << 16);
  pk.y = (unsigned)f2bf(v[2]) | ((unsigned)f2bf(v[3]) << 16);
  *(uint2*)d = pk;
}

// ---------------- K1q: Q projection GEMM (m97-style staging) ---------------------
__global__ __launch_bounds__(256) void k_projq(const unsigned short* __restrict__ xT,
                                               const unsigned short* __restrict__ Wqkv,
                                               unsigned short* __restrict__ SqT) {
  __shared__ unsigned short lds[18432];
  const int tid = threadIdx.x, lane = tid & 63, wave = tid >> 6;
  const int lr = lane & 15, lg = lane >> 4;
  const int n0 = blockIdx.x * 128, m0 = blockIdx.y * 128, b = blockIdx.z;
  const int wm = (wave >> 1) * 64, wn = (wave & 1) * 64;
  unsigned short* Wt = lds;
  unsigned short* Xt = lds + 8192;

  f32x4 zero = {0.f, 0.f, 0.f, 0.f};
  f32x4 acc[4][4];
#pragma unroll
  for (int mt = 0; mt < 4; ++mt)
#pragma unroll
    for (int nt = 0; nt < 4; ++nt) acc[mt][nt] = zero;

  const int sr = tid >> 3, sc = (tid & 7) * 8;
  const unsigned short* wsrc = Wqkv + (size_t)(m0 + sr) * Cn + sc;
  const unsigned short* xsrc = xT + (size_t)(b * Ln + n0 + sr) * Cn + sc;

  for (int kt = 0; kt < 4; ++kt) {
    const int k0 = kt * 64;
#pragma unroll
    for (int it = 0; it < 4; ++it) {
      gll16(wsrc + (size_t)(it * 32) * Cn + k0, Wt + it * 2048 + tid * 8);
      gll16(xsrc + (size_t)(it * 32) * Cn + k0, Xt + it * 2048 + tid * 8);
    }
    __syncthreads();
#pragma unroll
    for (int ks = 0; ks < 2; ++ks) {
      const int kc = ks * 32 + lg * 8;
      bf16x8 af[4], bfv[4];
#pragma unroll
      for (int mt = 0; mt < 4; ++mt)
        af[mt] = asbf(*(const us8*)(Wt + (wm + mt * 16 + lr) * 64 + kc));
#pragma unroll
      for (int nt = 0; nt < 4; ++nt)
        bfv[nt] = asbf(*(const us8*)(Xt + (wn + nt * 16 + lr) * 64 + kc));
#pragma unroll
      for (int mt = 0; mt < 4; ++mt)
#pragma unroll
        for (int nt = 0; nt < 4; ++nt) acc[mt][nt] = mfma16(af[mt], bfv[nt], acc[mt][nt]);
    }
    __syncthreads();
  }

  unsigned short* T = lds + wave * 4608;  // 64x72 per-wave transpose tile
#pragma unroll
  for (int mt = 0; mt < 4; ++mt)
#pragma unroll
    for (int nt = 0; nt < 4; ++nt) {
      int ll = nt * 16 + lr, ii = mt * 16 + lg * 4;
      uint2 pk;
      pk.x = (unsigned)f2bf(acc[mt][nt][0]) | ((unsigned)f2bf(acc[mt][nt][1]) << 16);
      pk.y = (unsigned)f2bf(acc[mt][nt][2]) | ((unsigned)f2bf(acc[mt][nt][3]) << 16);
      *(uint2*)&T[ll * 72 + ii] = pk;
    }
  __syncthreads();
#pragma unroll
  for (int p = 0; p < 8; ++p) {
    int ll = p * 8 + (lane >> 3), s = lane & 7;
    uint4 v = *(const uint4*)&T[ll * 72 + s * 8];
    *(uint4*)&SqT[(size_t)(b * Ln + n0 + wn + ll) * IN + m0 + wm + s * 8] = v;
  }
}

// ---------------- K1kv: fused KV projection + exp + context ----------------------
// per (h, 512-l tile, b): project k (64 d) and v (64 m) rows, exp(k) in-register,
// re-fragment via LDS, ctx GEMM over l, accumulate D[m][d] in regs, atomics once.
__global__ __launch_bounds__(256) void k_projkv(const unsigned short* __restrict__ xT,
                                                const unsigned short* __restrict__ Wqkv,
                                                float* __restrict__ ctxT,
                                                float* __restrict__ den) {
  __shared__ unsigned short lds[17408];  // staging 16384 || ek/vt 2*64*136
  unsigned short* Wt = lds;              // [128][64] (rows 0-63 = k-head, 64-127 = v-head)
  unsigned short* Xt = lds + 8192;       // [128][64]
  unsigned short* ek = lds;              // [64][136] exp(k) bf16, d-major
  unsigned short* vt = lds + 64 * 136;   // [64][136] v bf16, m-major
  const int tid = threadIdx.x, lane = tid & 63, wave = tid >> 6;
  const int lr = lane & 15, lg = lane >> 4;
  const int h = blockIdx.y, b = blockIdx.z;
  const int l0 = blockIdx.x * 512;
  const int wm = (wave >> 1) * 64, wn = (wave & 1) * 64;
  const int sr = tid >> 3, sc = (tid & 7) * 8;
  f32x4 zero = {0.f, 0.f, 0.f, 0.f};

  f32x4 cacc[4];
  cacc[0] = zero; cacc[1] = zero; cacc[2] = zero; cacc[3] = zero;
  float dacc[4][4] = {};

  for (int sub = 0; sub < 4; ++sub) {
    const int ls = l0 + sub * 128;
    f32x4 acc[4][4];
#pragma unroll
    for (int mt = 0; mt < 4; ++mt)
#pragma unroll
      for (int nt = 0; nt < 4; ++nt) acc[mt][nt] = zero;

    const unsigned short* xsrc = xT + (size_t)(b * Ln + ls + sr) * Cn + sc;
    for (int kt = 0; kt < 4; ++kt) {
      const int k0 = kt * 64;
#pragma unroll
      for (int it = 0; it < 4; ++it) {
        int gr = (it < 2 ? 512 : 960) + h * 64 + it * 32 + sr;  // k rows then v rows
        gll16(Wqkv + (size_t)gr * Cn + k0 + sc, Wt + it * 2048 + tid * 8);
        gll16(xsrc + (size_t)(it * 32) * Cn + k0, Xt + it * 2048 + tid * 8);
      }
      __syncthreads();
#pragma unroll
      for (int ks = 0; ks < 2; ++ks) {
        const int kc = ks * 32 + lg * 8;
        bf16x8 af[4], bfv[4];
#pragma unroll
        for (int mt = 0; mt < 4; ++mt)
          af[mt] = asbf(*(const us8*)(Wt + (wm + mt * 16 + lr) * 64 + kc));
#pragma unroll
        for (int nt = 0; nt < 4; ++nt)
          bfv[nt] = asbf(*(const us8*)(Xt + (wn + nt * 16 + lr) * 64 + kc));
#pragma unroll
        for (int mt = 0; mt < 4; ++mt)
#pragma unroll
          for (int nt = 0; nt < 4; ++nt) acc[mt][nt] = mfma16(af[mt], bfv[nt], acc[mt][nt]);
      }
      __syncthreads();
    }

    // epilogue: exp(k)->ek, v->vt (aliases staging; safe after final sync above)
    if (wave < 2) {
#pragma unroll
      for (int mt = 0; mt < 4; ++mt)
#pragma unroll
        for (int nt = 0; nt < 4; ++nt) {
          int lcol = wn + nt * 16 + lr;
#pragma unroll
          for (int r = 0; r < 4; ++r) {
            float e = __expf(acc[mt][nt][r]);
            dacc[mt][r] += e;
            ek[(mt * 16 + lg * 4 + r) * 136 + lcol] = f2bf(e);
          }
        }
    } else {
#pragma unroll
      for (int mt = 0; mt < 4; ++mt)
#pragma unroll
        for (int nt = 0; nt < 4; ++nt) {
          int lcol = wn + nt * 16 + lr;
#pragma unroll
          for (int r = 0; r < 4; ++r)
            vt[(mt * 16 + lg * 4 + r) * 136 + lcol] = f2bf(acc[mt][nt][r]);
        }
    }
    __syncthreads();

    // ctx GEMM: D[m][d] += sum_l vt[m][l] * ek[d][l], K=128
    const int mq = wave * 16;
#pragma unroll
    for (int ks = 0; ks < 4; ++ks) {
      const int kc = ks * 32 + lg * 8;
      bf16x8 a = asbf(*(const us8*)(vt + (mq + lr) * 136 + kc));
#pragma unroll
      for (int dt = 0; dt < 4; ++dt) {
        bf16x8 bb = asbf(*(const us8*)(ek + (dt * 16 + lr) * 136 + kc));
        cacc[dt] = mfma16(a, bb, cacc[dt]);
      }
    }
    __syncthreads();
  }

  // den: reduce over lr lanes, atomic per d
  if (wave < 2) {
#pragma unroll
    for (int mt = 0; mt < 4; ++mt)
#pragma unroll
      for (int r = 0; r < 4; ++r) {
        float v = dacc[mt][r];
        v += __shfl_xor(v, 1);
        v += __shfl_xor(v, 2);
        v += __shfl_xor(v, 4);
        v += __shfl_xor(v, 8);
        if (lr == 0) atomicAdd(&den[(b * Hn + h) * 64 + mt * 16 + lg * 4 + r], v);
      }
  }
  // ctx atomics: D rows m = mq+lg*4+r, cols d = dt*16+lr
  float* cb = ctxT + (size_t)(b * Hn + h) * 4096;
  const int mq = wave * 16;
#pragma unroll
  for (int dt = 0; dt < 4; ++dt)
#pragma unroll
    for (int r = 0; r < 4; ++r)
      atomicAdd(&cb[(mq + lg * 4 + r) * 64 + dt * 16 + lr], cacc[dt][r]);
}

// ---------------- K2: normalize context -> fragment-ready bf16 -------------------
__global__ __launch_bounds__(256) void k_nrm(const float* __restrict__ ctxT,
                                             const float* __restrict__ den,
                                             unsigned short* __restrict__ ctxb) {
  const int bh = blockIdx.x, t = threadIdx.x;
  const int m = t >> 2, dq = (t & 3) * 16;
  const float* src = ctxT + (size_t)bh * 4096 + m * 64 + dq;
  const float* dn = den + bh * 64 + dq;
  unsigned short o[16];
#pragma unroll
  for (int q = 0; q < 4; ++q) {
    f32x4 c = *(const f32x4*)(src + q * 4);
    f32x4 d4 = *(const f32x4*)(dn + q * 4);
#pragma unroll
    for (int j = 0; j < 4; ++j) o[q * 4 + j] = f2bf(c[j] / d4[j]);
  }
  uint4* dst = (uint4*)(ctxb + (size_t)bh * 4096 + m * 64 + dq);
  uint4 p0, p1;
  p0.x = (unsigned)o[0] | ((unsigned)o[1] << 16);
  p0.y = (unsigned)o[2] | ((unsigned)o[3] << 16);
  p0.z = (unsigned)o[4] | ((unsigned)o[5] << 16);
  p0.w = (unsigned)o[6] | ((unsigned)o[7] << 16);
  p1.x = (unsigned)o[8] | ((unsigned)o[9] << 16);
  p1.y = (unsigned)o[10] | ((unsigned)o[11] << 16);
  p1.z = (unsigned)o[12] | ((unsigned)o[13] << 16);
  p1.w = (unsigned)o[14] | ((unsigned)o[15] << 16);
  dst[0] = p0;
  dst[1] = p1;
}

// ---------------- K3: q-softmax + out-GEMM + output projection -------------------
__global__ __launch_bounds__(256) void k_out(const unsigned short* __restrict__ SqT,
                                             const unsigned short* __restrict__ ctxb,
                                             const unsigned short* __restrict__ Wob,
                                             const float* __restrict__ bo,
                                             float* __restrict__ out) {
  __shared__ unsigned short ot[64 * IN];  // [l][i] bf16, XOR-swizzled 16B slots
  const int tid = threadIdx.x, lane = tid & 63, w = tid >> 6;
  const int lr = lane & 15, lg = lane >> 4;
  const int l0 = blockIdx.x * 64, b = blockIdx.y;
  f32x4 zero = {0.f, 0.f, 0.f, 0.f};

  const unsigned short* qb = SqT + (size_t)(b * Ln + l0 + w * 16 + lr) * IN + lg * 8;
  us8 r0 = *(const us8*)qb;
  us8 r1 = *(const us8*)(qb + 32);
  for (int h = 0; h < Hn; ++h) {
    us8 n0, n1;
    if (h < 7) {
      n0 = *(const us8*)(qb + (h + 1) * 64);
      n1 = *(const us8*)(qb + (h + 1) * 64 + 32);
    }
    float qv[16];
#pragma unroll
    for (int j = 0; j < 8; ++j) {
      qv[j] = bf2f(r0[j]);
      qv[8 + j] = bf2f(r1[j]);
    }
    float mx = qv[0];
#pragma unroll
    for (int j = 1; j < 16; ++j) mx = fmaxf(mx, qv[j]);
    mx = fmaxf(mx, __shfl_xor(mx, 16));
    mx = fmaxf(mx, __shfl_xor(mx, 32));
    float sm = 0.f;
#pragma unroll
    for (int j = 0; j < 16; ++j) {
      qv[j] = __expf(qv[j] - mx);
      sm += qv[j];
    }
    sm += __shfl_xor(sm, 16);
    sm += __shfl_xor(sm, 32);
    float rs = 1.0f / sm;
    us8 a0u, a1u;
#pragma unroll
    for (int j = 0; j < 8; ++j) {
      a0u[j] = f2bf(qv[j] * rs);
      a1u[j] = f2bf(qv[8 + j] * rs);
    }
    bf16x8 a0 = asbf(a0u), a1 = asbf(a1u);
    const unsigned short* cbb = ctxb + (size_t)(b * Hn + h) * 4096;
#pragma unroll
    for (int mt = 0; mt < 4; ++mt) {
      bf16x8 bu0 = asbf(*(const us8*)(cbb + (mt * 16 + lr) * 64 + lg * 8));
      bf16x8 bu1 = asbf(*(const us8*)(cbb + (mt * 16 + lr) * 64 + 32 + lg * 8));
      f32x4 oa = mfma16(a0, bu0, zero);
      oa = mfma16(a1, bu1, oa);
      int ib = h * 64 + mt * 16 + lr;
#pragma unroll
      for (int r = 0; r < 4; ++r) {
        int ll = w * 16 + lg * 4 + r;
        ot[(ll * IN + ib) ^ ((ll & 7) << 3)] = f2bf(oa[r]);
      }
    }
    r0 = n0;
    r1 = n1;
  }
  __syncthreads();

  f32x4 acc[4][4];
#pragma unroll
  for (int mt = 0; mt < 4; ++mt)
#pragma unroll
    for (int nt = 0; nt < 4; ++nt) acc[mt][nt] = zero;
  const unsigned short* wB = Wob + (size_t)(w * 64 + lr) * IN;
#pragma unroll 2
  for (int ks = 0; ks < 16; ++ks) {
    int kc = ks * 32 + lg * 8;
    bf16x8 af[4], bf4[4];
#pragma unroll
    for (int mt = 0; mt < 4; ++mt) af[mt] = asbf(*(const us8*)(wB + mt * 16 * IN + kc));
#pragma unroll
    for (int nt = 0; nt < 4; ++nt) {
      int ll = nt * 16 + lr;
      bf4[nt] = asbf(*(const us8*)&ot[(ll * IN + kc) ^ ((ll & 7) << 3)]);
    }
#pragma unroll
    for (int mt = 0; mt < 4; ++mt)
#pragma unroll
      for (int nt = 0; nt < 4; ++nt) acc[mt][nt] = mfma16(af[mt], bf4[nt], acc[mt][nt]);
  }
#pragma unroll
  for (int mt = 0; mt < 4; ++mt) {
    int c = w * 64 + mt * 16 + lg * 4;
#pragma unroll
    for (int r = 0; r < 4; ++r) {
      float bb = bo[c + r];
      float* op = out + (size_t)(b * Cn + c + r) * Ln + l0;
#pragma unroll
      for (int nt = 0; nt < 4; ++nt) op[nt * 16 + lr] = acc[mt][nt][r] + bb;
    }
  }
}

extern "C" void kernel_launch(void* const* d_in, const int* in_sizes, int n_in,
                              void* d_out, int out_size, void* d_ws, size_t ws_size,
                              hipStream_t stream) {
  const float* x = (const float*)d_in[0];
  const float* Wq = (const float*)d_in[1];
  const float* Wk = (const float*)d_in[2];
  const float* Wv = (const float*)d_in[3];
  const float* Wo = (const float*)d_in[4];
  const float* bo = (const float*)d_in[5];
  float* out = (float*)d_out;

  char* ws = (char*)d_ws;
  size_t o = 0;
  unsigned short* xT = (unsigned short*)(ws + o);   o += (size_t)Bn * Ln * Cn * 2;   // 33.5 MB
  unsigned short* Wqkv = (unsigned short*)(ws + o); o += (size_t)1536 * Cn * 2;      // 768 KB
  unsigned short* Wob = (unsigned short*)(ws + o);  o += (size_t)Cn * IN * 2;        // 256 KB
  unsigned short* SqT = (unsigned short*)(ws + o);  o += (size_t)Bn * Ln * IN * 2;   // 67 MB
  float* ctxT = (float*)(ws + o);                   o += (size_t)Bn * Hn * 64 * 64 * 4;  // 1 MB
  float* den = (float*)(ws + o);                    o += (size_t)Bn * Hn * 64 * 4;       // 16 KB
  unsigned short* ctxb = (unsigned short*)(ws + o); o += (size_t)Bn * Hn * 64 * 64 * 2;  // 0.5 MB

  hipMemsetAsync(ctxT, 0, (size_t)Bn * Hn * 64 * 64 * 4 + (size_t)Bn * Hn * 64 * 4, stream);
  k_xt<<<dim3(Ln / 64, Cn / 64, Bn), 256, 0, stream>>>(x, xT);
  k_wcv<<<512, 256, 0, stream>>>(Wq, Wk, Wv, Wo, Wqkv, Wob);
  k_projq<<<dim3(Ln / 128, 4, Bn), 256, 0, stream>>>(xT, Wqkv, SqT);
  k_projkv<<<dim3(Ln / 512, Hn, Bn), 256, 0, stream>>>(xT, Wqkv, ctxT, den);
  k_nrm<<<Bn * Hn, 256, 0, stream>>>(ctxT, den, ctxb);
  k_out<<<dim3(Ln / 64, Bn), 256, 0, stream>>>(SqT, ctxb, Wob, bo, out);
}